// Round 2
// baseline (21950.362 us; speedup 1.0000x reference)
//
#include <hip/hip_runtime.h>
#include <hip/hip_bf16.h>

// MultilayerLSTMScan: B=128, T=1024, L=2, D=H=512.
// Design: persistent kernel, 256 WGs = 4 batch-groups x 64 column-groups.
// Weights (bf16, transposed, padded) live in LDS per-WG for the whole scan.
// Per round r: layer0 computes t=r, layer1 computes t=r-1 (skew) -> one
// per-batch-group barrier per round. h-state exchanged via device globals.

#define BB   128
#define TT   1024
#define DD   512
#define HH   512
#define NG4  2048           // 4*H
#define GB   4              // batch groups
#define GC   64             // column groups (sync domain size)
#define RB   32             // batch rows per WG   (BB/GB)
#define HC   8              // hidden cols per WG  (HH/GC)
#define NC   32             // gate cols per WG    (4*HC)
#define NWG  256
#define NTH  256
#define KPAD 536            // padded K stride (16B-aligned rows, ~2-way banks)
#define ZP   36             // z-exchange padded row
#define SMEM_BYTES (4*NC*KPAD*2 + 2*RB*ZP*4)   // 137216 + 9216 = 146432

typedef __bf16 bf16v8 __attribute__((ext_vector_type(8)));
typedef float  f32v4  __attribute__((ext_vector_type(4)));

__device__ unsigned short g_xbf[67108864];     // x as bf16 [B][T][D]
__device__ unsigned short g_hd0[2][BB * HH];   // masked h carry, layer0 (dbuf)
__device__ unsigned short g_hd1[2][BB * HH];   // masked h carry, layer1 (dbuf)
__device__ unsigned short g_nh0[2][BB * HH];   // fresh layer0 output (dbuf)
__device__ unsigned g_arrive[GB * 64];         // barrier counters, 256B apart
__device__ unsigned g_gen[GB * 64];

__device__ __forceinline__ unsigned short f2b(float f) {  // f32 -> bf16 RNE
  unsigned u = __builtin_bit_cast(unsigned, f);
  u += 0x7fffu + ((u >> 16) & 1u);
  return (unsigned short)(u >> 16);
}
__device__ __forceinline__ float sigm(float x) { return 1.f / (1.f + __expf(-x)); }
__device__ __forceinline__ float tanh_f(float x) {
  float e = __expf(2.f * x);            // saturates to +-1 without NaN
  return 1.f - 2.f / (e + 1.f);
}

// sense-reversing barrier over the GC workgroups of one batch group
__device__ __forceinline__ void group_barrier(int bg) {
  __syncthreads();
  if (threadIdx.x == 0) {
    __builtin_amdgcn_fence(__ATOMIC_RELEASE, "agent");
    unsigned* arr = &g_arrive[bg * 64];
    unsigned* gen = &g_gen[bg * 64];
    unsigned g = __hip_atomic_load(gen, __ATOMIC_RELAXED, __HIP_MEMORY_SCOPE_AGENT);
    unsigned old = __hip_atomic_fetch_add(arr, 1u, __ATOMIC_ACQ_REL, __HIP_MEMORY_SCOPE_AGENT);
    if (old == (unsigned)(GC - 1)) {
      __hip_atomic_store(arr, 0u, __ATOMIC_RELAXED, __HIP_MEMORY_SCOPE_AGENT);
      __hip_atomic_store(gen, g + 1u, __ATOMIC_RELEASE, __HIP_MEMORY_SCOPE_AGENT);
    } else {
      while (__hip_atomic_load(gen, __ATOMIC_RELAXED, __HIP_MEMORY_SCOPE_AGENT) == g)
        __builtin_amdgcn_s_sleep(1);
    }
    __builtin_amdgcn_fence(__ATOMIC_ACQUIRE, "agent");
  }
  __syncthreads();
}

extern "C" __global__ void __launch_bounds__(NTH, 1)
lstm_scan_kernel(const float* __restrict__ x,
                 const float* __restrict__ hmask,
                 const float* __restrict__ Wi,
                 const float* __restrict__ Wh,
                 const float* __restrict__ bias,
                 const float* __restrict__ c0in,
                 const float* __restrict__ h0in,
                 const int*   __restrict__ lens,
                 float* __restrict__ out) {
  extern __shared__ char smem[];
  unsigned short* wlds = (unsigned short*)smem;        // [4][NC][KPAD] bf16
  float* z0 = (float*)(smem + 4 * NC * KPAD * 2);      // [RB][ZP]
  float* z1 = z0 + RB * ZP;

  const int tid = threadIdx.x;
  const int bid = blockIdx.x;
  const int bg  = bid & (GB - 1);
  const int cg  = bid >> 2;

  // ---- prologue: weight slices -> LDS (bf16, transposed W[k][col] -> [n][k]) ----
  {
    const float* wsrc0 = Wi;
    const float* wsrc1 = Wh;
    const float* wsrc2 = Wi + (size_t)DD * NG4;
    const float* wsrc3 = Wh + (size_t)HH * NG4;
    const float* srcs[4] = {wsrc0, wsrc1, wsrc2, wsrc3};
    for (int m = 0; m < 4; ++m) {
      const float* W = srcs[m];
      for (int it = 0; it < 64; ++it) {
        int idx = it * NTH + tid;
        int k = idx >> 5;
        int n = idx & 31;                               // gate*8 + hid
        int gcolw = (n >> 3) * HH + cg * HC + (n & 7);  // global gate column
        wlds[(m * NC + n) * KPAD + k] = f2b(W[(size_t)k * NG4 + gcolw]);
      }
    }
  }

  // ---- prologue: convert this batch-group's x slab to bf16 (disjoint per group) ----
  {
    const float4* xf4 = (const float4*)x;
    uint2* xd = (uint2*)g_xbf;
    const size_t base = (size_t)bg * RB * TT * DD / 4;
    for (int it = 0; it < (RB * TT * DD / 4) / (GC * NTH); ++it) {
      size_t j = base + (size_t)it * (GC * NTH) + (size_t)cg * NTH + tid;
      float4 v = xf4[j];
      uint2 p;
      p.x = (unsigned)f2b(v.x) | ((unsigned)f2b(v.y) << 16);
      p.y = (unsigned)f2b(v.z) | ((unsigned)f2b(v.w) << 16);
      xd[j] = p;
    }
  }

  // ---- per-thread (row, hidden-col) state ----
  const int row   = tid >> 3;            // 0..31
  const int hid   = tid & 7;             // 0..7
  const int bglob = bg * RB + row;
  const int gcol  = cg * HC + hid;
  const int sidx  = bglob * HH + gcol;

  const float m0 = hmask[sidx];
  const float m1 = hmask[BB * HH + sidx];
  float c0c = c0in[sidx];
  float c1c = c0in[BB * HH + sidx];
  float h0c = h0in[sidx];
  float h1c = h0in[BB * HH + sidx];
  const int len = lens[bglob];
  const float bi00 = bias[0 * HH + gcol], bi01 = bias[1 * HH + gcol];
  const float bi02 = bias[2 * HH + gcol], bi03 = bias[3 * HH + gcol];
  const float bi10 = bias[NG4 + 0 * HH + gcol], bi11 = bias[NG4 + 1 * HH + gcol];
  const float bi12 = bias[NG4 + 2 * HH + gcol], bi13 = bias[NG4 + 3 * HH + gcol];

  g_hd0[0][sidx] = f2b(h0c * m0);   // initial masked carries
  g_hd1[0][sidx] = f2b(h1c * m1);

  // ---- wave tiling: 4 waves = 2 row-halves x 2 col-halves of [32x32] z tile ----
  const int lane = tid & 63;
  const int wv = tid >> 6;
  const int wr = wv & 1;
  const int wn = wv >> 1;
  const int am = lane & 15;                 // A row within tile
  const int ko = (lane >> 4) * 8;           // k offset within 32-block
  const int arow = bg * RB + wr * 16 + am;  // global batch row for A frags
  const size_t xrow_base = (size_t)arow * TT * DD + ko;
  const int hoff = arow * HH + ko;
  const int bnc = wn * 16 + (lane & 15);    // B/D col within WG tile
  const unsigned short* wp0 = wlds + (size_t)(0 * NC + bnc) * KPAD + ko;
  const unsigned short* wp1 = wlds + (size_t)(1 * NC + bnc) * KPAD + ko;
  const unsigned short* wp2 = wlds + (size_t)(2 * NC + bnc) * KPAD + ko;
  const unsigned short* wp3 = wlds + (size_t)(3 * NC + bnc) * KPAD + ko;
  const int zr = wr * 16 + (lane >> 4) * 4; // D row base (row=(lane>>4)*4+reg)
  float* z0w = z0 + zr * ZP + bnc;
  float* z1w = z1 + zr * ZP + bnc;
  const float* z0r = z0 + row * ZP + hid;
  const float* z1r = z1 + row * ZP + hid;
  float* outp = out + (size_t)bglob * TT * HH + gcol;

  __syncthreads();
  group_barrier(bg);   // x slab + initial carries visible group-wide

  for (int r = 0; r <= TT; ++r) {
    f32v4 acc0 = {0.f, 0.f, 0.f, 0.f};
    f32v4 acc1 = {0.f, 0.f, 0.f, 0.f};
    if (r < TT) {   // layer 0, t = r:  z0 = x_t@Wi0 + hd0@Wh0
      const unsigned short* xp = g_xbf + xrow_base + (size_t)r * DD;
      const unsigned short* hp = g_hd0[r & 1] + hoff;
#pragma unroll
      for (int kb = 0; kb < 16; ++kb) {
        bf16v8 a0 = *(const bf16v8*)(xp + kb * 32);
        bf16v8 w0 = *(const bf16v8*)(wp0 + kb * 32);
        acc0 = __builtin_amdgcn_mfma_f32_16x16x32_bf16(a0, w0, acc0, 0, 0, 0);
        bf16v8 a1 = *(const bf16v8*)(hp + kb * 32);
        bf16v8 w1 = *(const bf16v8*)(wp1 + kb * 32);
        acc0 = __builtin_amdgcn_mfma_f32_16x16x32_bf16(a1, w1, acc0, 0, 0, 0);
      }
    }
    if (r >= 1) {   // layer 1, s = r-1:  z1 = nh0(s)@Wi1 + hd1@Wh1
      const unsigned short* np = g_nh0[(r - 1) & 1] + hoff;
      const unsigned short* hp = g_hd1[(r - 1) & 1] + hoff;
#pragma unroll
      for (int kb = 0; kb < 16; ++kb) {
        bf16v8 a0 = *(const bf16v8*)(np + kb * 32);
        bf16v8 w2 = *(const bf16v8*)(wp2 + kb * 32);
        acc1 = __builtin_amdgcn_mfma_f32_16x16x32_bf16(a0, w2, acc1, 0, 0, 0);
        bf16v8 a1 = *(const bf16v8*)(hp + kb * 32);
        bf16v8 w3 = *(const bf16v8*)(wp3 + kb * 32);
        acc1 = __builtin_amdgcn_mfma_f32_16x16x32_bf16(a1, w3, acc1, 0, 0, 0);
      }
    }
    // scatter z frags to LDS (D layout: col=lane&15, row=(lane>>4)*4+reg)
    if (r < TT) {
      z0w[0 * ZP] = acc0[0]; z0w[1 * ZP] = acc0[1];
      z0w[2 * ZP] = acc0[2]; z0w[3 * ZP] = acc0[3];
    }
    if (r >= 1) {
      z1w[0 * ZP] = acc1[0]; z1w[1 * ZP] = acc1[1];
      z1w[2 * ZP] = acc1[2]; z1w[3 * ZP] = acc1[3];
    }
    __syncthreads();
    // gate math + state update (thread owns one (row, hidden col) pair)
    if (r < TT) {
      float zi = z0r[0]  + bi00;
      float zf = z0r[8]  + bi01;
      float zg = z0r[16] + bi02;
      float zo = z0r[24] + bi03;
      float ncl = sigm(zf) * c0c + sigm(zi) * tanh_f(zg);
      float nh  = sigm(zo) * tanh_f(ncl);
      if (r < len) { c0c = ncl; h0c = nh; }        // carry is length-masked
      g_nh0[r & 1][sidx]       = f2b(nh);          // vertical input: fresh nh
      g_hd0[(r + 1) & 1][sidx] = f2b(h0c * m0);    // recurrent: masked carry
    }
    if (r >= 1) {
      int s = r - 1;
      float zi = z1r[0]  + bi10;
      float zf = z1r[8]  + bi11;
      float zg = z1r[16] + bi12;
      float zo = z1r[24] + bi13;
      float ncl = sigm(zf) * c1c + sigm(zi) * tanh_f(zg);
      float nh  = sigm(zo) * tanh_f(ncl);
      if (s < len) { c1c = ncl; h1c = nh; }
      g_hd1[r & 1][sidx] = f2b(h1c * m1);
      outp[(size_t)s * HH] = nh;                   // emitted output is fresh nh
    }
    group_barrier(bg);
  }
}

extern "C" void kernel_launch(void* const* d_in, const int* in_sizes, int n_in,
                              void* d_out, int out_size, void* d_ws, size_t ws_size,
                              hipStream_t stream) {
  const float* x    = (const float*)d_in[0];
  const float* hm   = (const float*)d_in[1];
  const float* Wi   = (const float*)d_in[2];
  const float* Wh   = (const float*)d_in[3];
  const float* b    = (const float*)d_in[4];
  const float* c0   = (const float*)d_in[5];
  const float* h0   = (const float*)d_in[6];
  const int*   lens = (const int*)d_in[7];
  float* out = (float*)d_out;
  (void)in_sizes; (void)n_in; (void)out_size; (void)d_ws; (void)ws_size;

  static_assert(SMEM_BYTES <= 160 * 1024, "LDS budget");
  (void)hipFuncSetAttribute((const void*)lstm_scan_kernel,
                            hipFuncAttributeMaxDynamicSharedMemorySize, SMEM_BYTES);
  lstm_scan_kernel<<<dim3(NWG), dim3(NTH), SMEM_BYTES, stream>>>(
      x, hm, Wi, Wh, b, c0, h0, lens, out);
}